// Round 8
// baseline (240.669 us; speedup 1.0000x reference)
//
#include <hip/hip_runtime.h>
#include <stdint.h>

#define Bsz 2
#define Tseq 2048
#define Dmodel 1024
#define Hn 16
#define DKd 64

typedef __bf16 bf16;
typedef bf16 bf16x8 __attribute__((ext_vector_type(8)));
typedef float f32x4 __attribute__((ext_vector_type(4)));

// async global->LDS, 16B per lane. LDS dest must be wave-uniform base + lane*16
// and contiguous across the wave's lanes (no padding on DMA'd tiles).
__device__ inline void gld_lds16(const void* g, void* l) {
  __builtin_amdgcn_global_load_lds(
      (const __attribute__((address_space(1))) uint32_t*)g,
      (__attribute__((address_space(3))) uint32_t*)l, 16, 0, 0);
}

// pack 4 fp32 -> 4 bf16, single 8B store
__device__ inline void pack4_store(bf16* dst, float a, float b, float c, float d) {
  union { bf16 h[4]; uint2 u; } pk;
  pk.h[0] = (bf16)a; pk.h[1] = (bf16)b; pk.h[2] = (bf16)c; pk.h[3] = (bf16)d;
  *(uint2*)dst = pk.u;
}

// ---------------- fp32 -> bf16 convert (activations + weights) ----------------
struct CvtArgs {
  const float* src[7];
  bf16* dst[7];
  int n4[7];
};

__global__ void __launch_bounds__(256) cvt_f32_bf16(CvtArgs a) {
  const int z = blockIdx.y;
  const float4* s = (const float4*)a.src[z];
  uint2* d = (uint2*)a.dst[z];
  const int n4 = a.n4[z];
  for (int i = blockIdx.x * 256 + threadIdx.x; i < n4; i += gridDim.x * 256) {
    float4 v = s[i];
    union { bf16 h[4]; uint2 u; } pk;
    pk.h[0] = (bf16)v.x; pk.h[1] = (bf16)v.y;
    pk.h[2] = (bf16)v.z; pk.h[3] = (bf16)v.w;
    d[i] = pk.u;
  }
}

// ---------------- QKV GEMM: C = (A * W^T + bias)*scale, bf16 in --------------
// 128x128 tile, BK=32, XCD-swizzled 1D grid (n-tiles sharing an A m-tile land
// on one XCD -> A from L2). mode 0: bf16 [B,H,T,DK]; mode 1: bf16 [B,H,DK,T].
struct GemmArgs {
  const bf16* A[3];
  const bf16* W[3];
  const float* bias[3];
  void* out[3];
  int mode[3];
  float scale[3];
};

__global__ void __launch_bounds__(256) gemm_qkv(GemmArgs g) {
  const int l = blockIdx.x;
  const int z = l >> 8;           // 768 = 3 * 256
  const int r = l & 255;
  const int mt = (r & 7) * 4 + (r >> 6);  // [0,32)
  const int nt = (r >> 3) & 7;            // [0,8)
  const bf16* __restrict__ A = g.A[z];
  const bf16* __restrict__ W = g.W[z];
  const float* __restrict__ bias = g.bias[z];
  const int mode = g.mode[z];
  const float scl = g.scale[z];

  __shared__ __align__(16) bf16 As[128 * 32];
  __shared__ __align__(16) bf16 Bs[128 * 32];

  const int tid = threadIdx.x;
  const int w = tid >> 6, lane = tid & 63;
  const int l15 = lane & 15, quad = lane >> 4;
  const int wm = (w >> 1) * 64, wn = (w & 1) * 64;
  const int m0 = mt * 128, n0 = nt * 128;

  f32x4 zero = {0.f, 0.f, 0.f, 0.f};
  f32x4 acc[4][4];
#pragma unroll
  for (int mi = 0; mi < 4; ++mi)
#pragma unroll
    for (int ni = 0; ni < 4; ++ni) acc[mi][ni] = zero;

  for (int k0 = 0; k0 < Dmodel; k0 += 32) {
    __syncthreads();
#pragma unroll
    for (int p = 0; p < 2; ++p) {
      const int c = p * 256 + tid;
      const int row = c >> 2, ko = (c & 3) * 8;
      gld_lds16(A + (size_t)(m0 + row) * Dmodel + k0 + ko, (void*)(As + c * 8));
      gld_lds16(W + (size_t)(n0 + row) * Dmodel + k0 + ko, (void*)(Bs + c * 8));
    }
    __syncthreads();

    bf16x8 af[4], bfr[4];
#pragma unroll
    for (int i = 0; i < 4; ++i) {
      af[i]  = *(const bf16x8*)(As + (wm + i * 16 + l15) * 32 + quad * 8);
      bfr[i] = *(const bf16x8*)(Bs + (wn + i * 16 + l15) * 32 + quad * 8);
    }
#pragma unroll
    for (int mi = 0; mi < 4; ++mi)
#pragma unroll
      for (int ni = 0; ni < 4; ++ni)
        acc[mi][ni] = __builtin_amdgcn_mfma_f32_16x16x32_bf16(af[mi], bfr[ni],
                                                              acc[mi][ni], 0, 0, 0);
  }

#pragma unroll
  for (int mi = 0; mi < 4; ++mi) {
#pragma unroll
    for (int r2 = 0; r2 < 4; ++r2) {
      const int m = m0 + wm + mi * 16 + quad * 4 + r2;
      const int bb = m >> 11, tt = m & 2047;
#pragma unroll
      for (int ni = 0; ni < 4; ++ni) {
        const int n = n0 + wn + ni * 16 + l15;
        const float val = (acc[mi][ni][r2] + bias[n]) * scl;
        bf16* o = (bf16*)g.out[z];
        const int hh = n >> 6, dk = n & 63;
        if (mode == 0) {
          o[((size_t)(bb * Hn + hh) * Tseq + tt) * DKd + dk] = (bf16)val;
        } else {
          o[((size_t)(bb * Hn + hh) * DKd + dk) * Tseq + tt] = (bf16)val;
        }
      }
    }
  }
}

// ---------------- out-projection GEMM, 64x128 tile, BK=32, XCD-swizzled ------
__global__ void __launch_bounds__(256) gemm_out64(const bf16* __restrict__ A,
                                                  const bf16* __restrict__ W,
                                                  const float* __restrict__ bias,
                                                  float* __restrict__ out) {
  const int l = blockIdx.x;                // 512 blocks
  const int mt = (l & 7) * 8 + (l >> 6);   // [0,64)
  const int nt = (l >> 3) & 7;             // [0,8)

  __shared__ __align__(16) bf16 As[64 * 32];
  __shared__ __align__(16) bf16 Bs[128 * 32];

  const int tid = threadIdx.x;
  const int w = tid >> 6, lane = tid & 63;
  const int l15 = lane & 15, quad = lane >> 4;
  const int wm = (w >> 1) * 32, wn = (w & 1) * 64;
  const int m0 = mt * 64, n0 = nt * 128;

  f32x4 zero = {0.f, 0.f, 0.f, 0.f};
  f32x4 acc[2][4];
#pragma unroll
  for (int mi = 0; mi < 2; ++mi)
#pragma unroll
    for (int ni = 0; ni < 4; ++ni) acc[mi][ni] = zero;

  for (int k0 = 0; k0 < Dmodel; k0 += 32) {
    __syncthreads();
    {
      const int c = tid;
      const int row = c >> 2, ko = (c & 3) * 8;
      gld_lds16(A + (size_t)(m0 + row) * Dmodel + k0 + ko, (void*)(As + c * 8));
    }
#pragma unroll
    for (int p = 0; p < 2; ++p) {
      const int c = p * 256 + tid;
      const int row = c >> 2, ko = (c & 3) * 8;
      gld_lds16(W + (size_t)(n0 + row) * Dmodel + k0 + ko, (void*)(Bs + c * 8));
    }
    __syncthreads();

    bf16x8 af[2], bfr[4];
#pragma unroll
    for (int i = 0; i < 2; ++i)
      af[i] = *(const bf16x8*)(As + (wm + i * 16 + l15) * 32 + quad * 8);
#pragma unroll
    for (int i = 0; i < 4; ++i)
      bfr[i] = *(const bf16x8*)(Bs + (wn + i * 16 + l15) * 32 + quad * 8);
#pragma unroll
    for (int mi = 0; mi < 2; ++mi)
#pragma unroll
      for (int ni = 0; ni < 4; ++ni)
        acc[mi][ni] = __builtin_amdgcn_mfma_f32_16x16x32_bf16(af[mi], bfr[ni],
                                                              acc[mi][ni], 0, 0, 0);
  }

#pragma unroll
  for (int mi = 0; mi < 2; ++mi)
#pragma unroll
    for (int r = 0; r < 4; ++r) {
      const int m = m0 + wm + mi * 16 + quad * 4 + r;
#pragma unroll
      for (int ni = 0; ni < 4; ++ni) {
        const int n = n0 + wn + ni * 16 + l15;
        out[(size_t)m * Dmodel + n] = acc[mi][ni][r] + bias[n];
      }
    }
}

// ---------------- fused causal attention (transposed-S, 32 q-rows/wave) -------
// Round-8 restructure: S^T = K*Q^T (operand swap; loads unchanged) so each lane
// holds 4 CONSECUTIVE keys for one q-row -> P round-trip is 8 ds_write_b64 not
// 32 ds_write_b16; PV is O^T = V^T*P^T with identical V/P read patterns; l is
// one scalar per lane. Each wave owns 32 q-rows (2 groups of 16): K-frags and
// V-frags serve both groups, staging/barriers per q-row halve. Diagonal tile
// computes only the live column-tiles.
__global__ void __launch_bounds__(256) attn_fused(const bf16* __restrict__ Q,
                                                  const bf16* __restrict__ K,
                                                  const bf16* __restrict__ Vt,
                                                  bf16* __restrict__ ctx) {
  __shared__ __align__(16) bf16 Ks[8 * 128 * 8];    // [kc][row][8]   16 KB
  __shared__ __align__(16) bf16 Vs[16 * 64 * 8];    // [jc][d][8]     16 KB
  __shared__ __align__(16) bf16 plds[4][32][136];   // per-wave P (2 groups) 34 KB

  const int tid = threadIdx.x;
  const int w = tid >> 6, lane = tid & 63;
  const int l15 = lane & 15, quad = lane >> 4;

  // longest-first: qt descending outer, (h,b) inner (stride 32 -> same XCD)
  const int l = blockIdx.x;                 // 512 blocks
  const int qt = 15 - (l >> 5);             // q-tile of 128 rows
  const int hb = l & 31;
  const int h = hb & 15, b = hb >> 4;
  const int bh = b * Hn + h;
  const int qb = qt * 128 + w * 32;         // group A rows qb.., group B qb+16..

  const bf16* Qb = Q + (size_t)bh * Tseq * DKd;
  const bf16* Kb = K + (size_t)bh * Tseq * DKd;
  const bf16* Vb = Vt + (size_t)bh * DKd * Tseq;

  // Q fragments (used as B-operand: n=l15 -> q-row, k=quad*8+j -> dk)
  bf16x8 aqA0 = *(const bf16x8*)(Qb + (size_t)(qb + l15) * DKd + quad * 8);
  bf16x8 aqA1 = *(const bf16x8*)(Qb + (size_t)(qb + l15) * DKd + 32 + quad * 8);
  bf16x8 aqB0 = *(const bf16x8*)(Qb + (size_t)(qb + 16 + l15) * DKd + quad * 8);
  bf16x8 aqB1 = *(const bf16x8*)(Qb + (size_t)(qb + 16 + l15) * DKd + 32 + quad * 8);

  f32x4 zero = {0.f, 0.f, 0.f, 0.f};
  f32x4 oaccA[4], oaccB[4];
#pragma unroll
  for (int nd = 0; nd < 4; ++nd) { oaccA[nd] = zero; oaccB[nd] = zero; }
  f32x4 laccA = zero, laccB = zero;

  bf16x8 onesf;
#pragma unroll
  for (int i = 0; i < 8; ++i) onesf[i] = (bf16)1.0f;

  for (int j0 = 0; j0 <= qt * 128; j0 += 128) {
    __syncthreads();  // prev tile's Ks/Vs reads done
#pragma unroll
    for (int p = 0; p < 4; ++p) {
      const int c = p * 256 + tid;
      gld_lds16(Kb + (size_t)(j0 + (c & 127)) * DKd + (c >> 7) * 8,
                (void*)(Ks + c * 8));
      gld_lds16(Vb + (size_t)(c & 63) * Tseq + j0 + (c >> 6) * 8,
                (void*)(Vs + c * 8));
    }
    __syncthreads();  // drains DMA

    if (j0 + 128 <= qb) {
      // ---------- fully unmasked tile ----------
      f32x4 sA[8], sB[8];
#pragma unroll
      for (int ct = 0; ct < 8; ++ct) { sA[ct] = zero; sB[ct] = zero; }
#pragma unroll
      for (int ct = 0; ct < 8; ++ct) {
        bf16x8 bk0 = *(const bf16x8*)(Ks + ((quad)*128 + ct * 16 + l15) * 8);
        bf16x8 bk1 = *(const bf16x8*)(Ks + ((4 + quad) * 128 + ct * 16 + l15) * 8);
        sA[ct] = __builtin_amdgcn_mfma_f32_16x16x32_bf16(bk0, aqA0, sA[ct], 0, 0, 0);
        sA[ct] = __builtin_amdgcn_mfma_f32_16x16x32_bf16(bk1, aqA1, sA[ct], 0, 0, 0);
        sB[ct] = __builtin_amdgcn_mfma_f32_16x16x32_bf16(bk0, aqB0, sB[ct], 0, 0, 0);
        sB[ct] = __builtin_amdgcn_mfma_f32_16x16x32_bf16(bk1, aqB1, sB[ct], 0, 0, 0);
      }
#pragma unroll
      for (int ct = 0; ct < 8; ++ct) {
        pack4_store(&plds[w][l15][ct * 16 + quad * 4],
                    exp2f(sA[ct][0]), exp2f(sA[ct][1]), exp2f(sA[ct][2]), exp2f(sA[ct][3]));
        pack4_store(&plds[w][16 + l15][ct * 16 + quad * 4],
                    exp2f(sB[ct][0]), exp2f(sB[ct][1]), exp2f(sB[ct][2]), exp2f(sB[ct][3]));
      }
#pragma unroll
      for (int kc = 0; kc < 4; ++kc) {
        bf16x8 bpA = *(const bf16x8*)(&plds[w][l15][kc * 32 + quad * 8]);
        bf16x8 bpB = *(const bf16x8*)(&plds[w][16 + l15][kc * 32 + quad * 8]);
        laccA = __builtin_amdgcn_mfma_f32_16x16x32_bf16(onesf, bpA, laccA, 0, 0, 0);
        laccB = __builtin_amdgcn_mfma_f32_16x16x32_bf16(onesf, bpB, laccB, 0, 0, 0);
#pragma unroll
        for (int nd = 0; nd < 4; ++nd) {
          bf16x8 bv = *(const bf16x8*)(Vs + ((kc * 4 + quad) * 64 + nd * 16 + l15) * 8);
          oaccA[nd] = __builtin_amdgcn_mfma_f32_16x16x32_bf16(bv, bpA, oaccA[nd], 0, 0, 0);
          oaccB[nd] = __builtin_amdgcn_mfma_f32_16x16x32_bf16(bv, bpB, oaccB[nd], 0, 0, 0);
        }
      }
    } else {
      // ---------- diagonal tile (j0 == qt*128): rel = qb - j0 = w*32 ----------
      const int ctfA = w * 2;        // partial column-tile for group A
      const int ctlA = ctfA + 1;     // live tiles group A
      const int ctfB = w * 2 + 1;    // partial for group B
      const int ctlB = ctfB + 1;     // live tiles group B
      const int kclim = w + 1;       // live PV k-chunks (both groups)
      for (int ct = 0; ct < ctlB; ++ct) {
        bf16x8 bk0 = *(const bf16x8*)(Ks + ((quad)*128 + ct * 16 + l15) * 8);
        bf16x8 bk1 = *(const bf16x8*)(Ks + ((4 + quad) * 128 + ct * 16 + l15) * 8);
        if (ct < ctlA) {
          f32x4 s = zero;
          s = __builtin_amdgcn_mfma_f32_16x16x32_bf16(bk0, aqA0, s, 0, 0, 0);
          s = __builtin_amdgcn_mfma_f32_16x16x32_bf16(bk1, aqA1, s, 0, 0, 0);
          float p[4];
#pragma unroll
          for (int r = 0; r < 4; ++r) {
            p[r] = exp2f(s[r]);
            if (ct == ctfA && (ct * 16 + quad * 4 + r > w * 32 + l15)) p[r] = 0.f;
          }
          pack4_store(&plds[w][l15][ct * 16 + quad * 4], p[0], p[1], p[2], p[3]);
        }
        {
          f32x4 s = zero;
          s = __builtin_amdgcn_mfma_f32_16x16x32_bf16(bk0, aqB0, s, 0, 0, 0);
          s = __builtin_amdgcn_mfma_f32_16x16x32_bf16(bk1, aqB1, s, 0, 0, 0);
          float p[4];
#pragma unroll
          for (int r = 0; r < 4; ++r) {
            p[r] = exp2f(s[r]);
            if (ct == ctfB && (ct * 16 + quad * 4 + r > w * 32 + 16 + l15)) p[r] = 0.f;
          }
          pack4_store(&plds[w][16 + l15][ct * 16 + quad * 4], p[0], p[1], p[2], p[3]);
        }
      }
      // zero-fill group A's ct = ctlA (read by PV kc < kclim); group B needs none
      pack4_store(&plds[w][l15][ctlA * 16 + quad * 4], 0.f, 0.f, 0.f, 0.f);
      for (int kc = 0; kc < kclim; ++kc) {
        bf16x8 bpA = *(const bf16x8*)(&plds[w][l15][kc * 32 + quad * 8]);
        bf16x8 bpB = *(const bf16x8*)(&plds[w][16 + l15][kc * 32 + quad * 8]);
        laccA = __builtin_amdgcn_mfma_f32_16x16x32_bf16(onesf, bpA, laccA, 0, 0, 0);
        laccB = __builtin_amdgcn_mfma_f32_16x16x32_bf16(onesf, bpB, laccB, 0, 0, 0);
#pragma unroll
        for (int nd = 0; nd < 4; ++nd) {
          bf16x8 bv = *(const bf16x8*)(Vs + ((kc * 4 + quad) * 64 + nd * 16 + l15) * 8);
          oaccA[nd] = __builtin_amdgcn_mfma_f32_16x16x32_bf16(bv, bpA, oaccA[nd], 0, 0, 0);
          oaccB[nd] = __builtin_amdgcn_mfma_f32_16x16x32_bf16(bv, bpB, oaccB[nd], 0, 0, 0);
        }
      }
    }
  }

  // epilogue: O^T lane layout = 4 consecutive d's (quad*4+r) for q-row l15
  const float invA = 1.0f / laccA[0];
  const float invB = 1.0f / laccB[0];
  bf16* cA = ctx + (size_t)(b * Tseq + qb + l15) * Dmodel + h * DKd + quad * 4;
  bf16* cB = ctx + (size_t)(b * Tseq + qb + 16 + l15) * Dmodel + h * DKd + quad * 4;
#pragma unroll
  for (int nd = 0; nd < 4; ++nd) {
    pack4_store(cA + nd * 16, oaccA[nd][0] * invA, oaccA[nd][1] * invA,
                oaccA[nd][2] * invA, oaccA[nd][3] * invA);
    pack4_store(cB + nd * 16, oaccB[nd][0] * invB, oaccB[nd][1] * invB,
                oaccB[nd][2] * invB, oaccB[nd][3] * invB);
  }
}

// -------------------------------- launcher ------------------------------------
extern "C" void kernel_launch(void* const* d_in, const int* in_sizes, int n_in,
                              void* d_out, int out_size, void* d_ws, size_t ws_size,
                              hipStream_t stream) {
  const float* q = (const float*)d_in[0];
  const float* k = (const float*)d_in[1];
  const float* v = (const float*)d_in[2];
  // d_in[3] = attn_mask (causal, known statically) - unused
  const float* Wq = (const float*)d_in[4];
  const float* bq = (const float*)d_in[5];
  const float* Wk = (const float*)d_in[6];
  const float* bk = (const float*)d_in[7];
  const float* Wv = (const float*)d_in[8];
  const float* bv = (const float*)d_in[9];
  const float* Wo = (const float*)d_in[10];
  const float* bo = (const float*)d_in[11];

  char* ws = (char*)d_ws;
  const size_t MB = 1024 * 1024;
  bf16* Wq_b = (bf16*)(ws + 0 * MB);
  bf16* Wk_b = (bf16*)(ws + 2 * MB);
  bf16* Wv_b = (bf16*)(ws + 4 * MB);
  bf16* Wo_b = (bf16*)(ws + 6 * MB);
  bf16* q_b  = (bf16*)(ws + 8 * MB);   // dead after QKV gemm
  bf16* k_b  = (bf16*)(ws + 16 * MB);
  bf16* v_b  = (bf16*)(ws + 24 * MB);
  bf16* Qh   = (bf16*)(ws + 32 * MB);  // [B,H,T,DK], pre-scaled
  bf16* Kh   = (bf16*)(ws + 40 * MB);  // [B,H,T,DK]
  bf16* Vt   = (bf16*)(ws + 48 * MB);  // [B,H,DK,T]
  bf16* ctx  = (bf16*)(ws + 8 * MB);   // aliases q_b (dead by then)

  const int NACT4 = (Bsz * Tseq * Dmodel) / 4;
  const int NW4 = (Dmodel * Dmodel) / 4;

  CvtArgs ca;
  ca.src[0] = q;  ca.dst[0] = q_b;  ca.n4[0] = NACT4;
  ca.src[1] = k;  ca.dst[1] = k_b;  ca.n4[1] = NACT4;
  ca.src[2] = v;  ca.dst[2] = v_b;  ca.n4[2] = NACT4;
  ca.src[3] = Wq; ca.dst[3] = Wq_b; ca.n4[3] = NW4;
  ca.src[4] = Wk; ca.dst[4] = Wk_b; ca.n4[4] = NW4;
  ca.src[5] = Wv; ca.dst[5] = Wv_b; ca.n4[5] = NW4;
  ca.src[6] = Wo; ca.dst[6] = Wo_b; ca.n4[6] = NW4;
  cvt_f32_bf16<<<dim3(512, 7), 256, 0, stream>>>(ca);

  const float SC = 0.125f * 1.4426950408889634f;  // 1/sqrt(DK) * log2(e)
  GemmArgs ga;
  ga.A[0] = q_b; ga.W[0] = Wq_b; ga.bias[0] = bq; ga.out[0] = Qh; ga.mode[0] = 0; ga.scale[0] = SC;
  ga.A[1] = k_b; ga.W[1] = Wk_b; ga.bias[1] = bk; ga.out[1] = Kh; ga.mode[1] = 0; ga.scale[1] = 1.f;
  ga.A[2] = v_b; ga.W[2] = Wv_b; ga.bias[2] = bv; ga.out[2] = Vt; ga.mode[2] = 1; ga.scale[2] = 1.f;
  gemm_qkv<<<dim3(768), 256, 0, stream>>>(ga);

  attn_fused<<<dim3((Tseq / 128) * Hn * Bsz), 256, 0, stream>>>(Qh, Kh, Vt, ctx);

  gemm_out64<<<dim3(512), 256, 0, stream>>>(ctx, Wo_b, bo, (float*)d_out);
}

// Round 9
// 230.379 us; speedup vs baseline: 1.0447x; 1.0447x over previous
//
#include <hip/hip_runtime.h>
#include <stdint.h>

#define Bsz 2
#define Tseq 2048
#define Dmodel 1024
#define Hn 16
#define DKd 64

typedef __bf16 bf16;
typedef bf16 bf16x8 __attribute__((ext_vector_type(8)));
typedef float f32x4 __attribute__((ext_vector_type(4)));

// async global->LDS, 16B per lane. LDS dest must be wave-uniform base + lane*16
// and contiguous across the wave's lanes (no padding on DMA'd tiles).
__device__ inline void gld_lds16(const void* g, void* l) {
  __builtin_amdgcn_global_load_lds(
      (const __attribute__((address_space(1))) uint32_t*)g,
      (__attribute__((address_space(3))) uint32_t*)l, 16, 0, 0);
}

// pack 4 fp32 -> 4 bf16, single 8B store
__device__ inline void pack4_store(bf16* dst, float a, float b, float c, float d) {
  union { bf16 h[4]; uint2 u; } pk;
  pk.h[0] = (bf16)a; pk.h[1] = (bf16)b; pk.h[2] = (bf16)c; pk.h[3] = (bf16)d;
  *(uint2*)dst = pk.u;
}

// ---------------- fp32 -> bf16 convert (activations + weights) ----------------
struct CvtArgs {
  const float* src[7];
  bf16* dst[7];
  int n4[7];
};

__global__ void __launch_bounds__(256) cvt_f32_bf16(CvtArgs a) {
  const int z = blockIdx.y;
  const float4* s = (const float4*)a.src[z];
  uint2* d = (uint2*)a.dst[z];
  const int n4 = a.n4[z];
  for (int i = blockIdx.x * 256 + threadIdx.x; i < n4; i += gridDim.x * 256) {
    float4 v = s[i];
    union { bf16 h[4]; uint2 u; } pk;
    pk.h[0] = (bf16)v.x; pk.h[1] = (bf16)v.y;
    pk.h[2] = (bf16)v.z; pk.h[3] = (bf16)v.w;
    d[i] = pk.u;
  }
}

// ---------------- QKV GEMM: C = (A * W^T + bias)*scale, bf16 in --------------
// 128x128 tile, BK=32, XCD-swizzled 1D grid (n-tiles sharing an A m-tile land
// on one XCD -> A from L2). mode 0: bf16 [B,H,T,DK]; mode 1: bf16 [B,H,DK,T].
struct GemmArgs {
  const bf16* A[3];
  const bf16* W[3];
  const float* bias[3];
  void* out[3];
  int mode[3];
  float scale[3];
};

__global__ void __launch_bounds__(256) gemm_qkv(GemmArgs g) {
  const int l = blockIdx.x;
  const int z = l >> 8;           // 768 = 3 * 256
  const int r = l & 255;
  const int mt = (r & 7) * 4 + (r >> 6);  // [0,32)
  const int nt = (r >> 3) & 7;            // [0,8)
  const bf16* __restrict__ A = g.A[z];
  const bf16* __restrict__ W = g.W[z];
  const float* __restrict__ bias = g.bias[z];
  const int mode = g.mode[z];
  const float scl = g.scale[z];

  __shared__ __align__(16) bf16 As[128 * 32];
  __shared__ __align__(16) bf16 Bs[128 * 32];

  const int tid = threadIdx.x;
  const int w = tid >> 6, lane = tid & 63;
  const int l15 = lane & 15, quad = lane >> 4;
  const int wm = (w >> 1) * 64, wn = (w & 1) * 64;
  const int m0 = mt * 128, n0 = nt * 128;

  f32x4 zero = {0.f, 0.f, 0.f, 0.f};
  f32x4 acc[4][4];
#pragma unroll
  for (int mi = 0; mi < 4; ++mi)
#pragma unroll
    for (int ni = 0; ni < 4; ++ni) acc[mi][ni] = zero;

  for (int k0 = 0; k0 < Dmodel; k0 += 32) {
    __syncthreads();
#pragma unroll
    for (int p = 0; p < 2; ++p) {
      const int c = p * 256 + tid;
      const int row = c >> 2, ko = (c & 3) * 8;
      gld_lds16(A + (size_t)(m0 + row) * Dmodel + k0 + ko, (void*)(As + c * 8));
      gld_lds16(W + (size_t)(n0 + row) * Dmodel + k0 + ko, (void*)(Bs + c * 8));
    }
    __syncthreads();

    bf16x8 af[4], bfr[4];
#pragma unroll
    for (int i = 0; i < 4; ++i) {
      af[i]  = *(const bf16x8*)(As + (wm + i * 16 + l15) * 32 + quad * 8);
      bfr[i] = *(const bf16x8*)(Bs + (wn + i * 16 + l15) * 32 + quad * 8);
    }
#pragma unroll
    for (int mi = 0; mi < 4; ++mi)
#pragma unroll
      for (int ni = 0; ni < 4; ++ni)
        acc[mi][ni] = __builtin_amdgcn_mfma_f32_16x16x32_bf16(af[mi], bfr[ni],
                                                              acc[mi][ni], 0, 0, 0);
  }

#pragma unroll
  for (int mi = 0; mi < 4; ++mi) {
#pragma unroll
    for (int r2 = 0; r2 < 4; ++r2) {
      const int m = m0 + wm + mi * 16 + quad * 4 + r2;
      const int bb = m >> 11, tt = m & 2047;
#pragma unroll
      for (int ni = 0; ni < 4; ++ni) {
        const int n = n0 + wn + ni * 16 + l15;
        const float val = (acc[mi][ni][r2] + bias[n]) * scl;
        bf16* o = (bf16*)g.out[z];
        const int hh = n >> 6, dk = n & 63;
        if (mode == 0) {
          o[((size_t)(bb * Hn + hh) * Tseq + tt) * DKd + dk] = (bf16)val;
        } else {
          o[((size_t)(bb * Hn + hh) * DKd + dk) * Tseq + tt] = (bf16)val;
        }
      }
    }
  }
}

// ---------------- out-projection GEMM, 64x128 tile, BK=32, XCD-swizzled ------
__global__ void __launch_bounds__(256) gemm_out64(const bf16* __restrict__ A,
                                                  const bf16* __restrict__ W,
                                                  const float* __restrict__ bias,
                                                  float* __restrict__ out) {
  const int l = blockIdx.x;                // 512 blocks
  const int mt = (l & 7) * 8 + (l >> 6);   // [0,64)
  const int nt = (l >> 3) & 7;             // [0,8)

  __shared__ __align__(16) bf16 As[64 * 32];
  __shared__ __align__(16) bf16 Bs[128 * 32];

  const int tid = threadIdx.x;
  const int w = tid >> 6, lane = tid & 63;
  const int l15 = lane & 15, quad = lane >> 4;
  const int wm = (w >> 1) * 32, wn = (w & 1) * 64;
  const int m0 = mt * 64, n0 = nt * 128;

  f32x4 zero = {0.f, 0.f, 0.f, 0.f};
  f32x4 acc[2][4];
#pragma unroll
  for (int mi = 0; mi < 2; ++mi)
#pragma unroll
    for (int ni = 0; ni < 4; ++ni) acc[mi][ni] = zero;

  for (int k0 = 0; k0 < Dmodel; k0 += 32) {
    __syncthreads();
    {
      const int c = tid;
      const int row = c >> 2, ko = (c & 3) * 8;
      gld_lds16(A + (size_t)(m0 + row) * Dmodel + k0 + ko, (void*)(As + c * 8));
    }
#pragma unroll
    for (int p = 0; p < 2; ++p) {
      const int c = p * 256 + tid;
      const int row = c >> 2, ko = (c & 3) * 8;
      gld_lds16(W + (size_t)(n0 + row) * Dmodel + k0 + ko, (void*)(Bs + c * 8));
    }
    __syncthreads();

    bf16x8 af[2], bfr[4];
#pragma unroll
    for (int i = 0; i < 2; ++i)
      af[i] = *(const bf16x8*)(As + (wm + i * 16 + l15) * 32 + quad * 8);
#pragma unroll
    for (int i = 0; i < 4; ++i)
      bfr[i] = *(const bf16x8*)(Bs + (wn + i * 16 + l15) * 32 + quad * 8);
#pragma unroll
    for (int mi = 0; mi < 2; ++mi)
#pragma unroll
      for (int ni = 0; ni < 4; ++ni)
        acc[mi][ni] = __builtin_amdgcn_mfma_f32_16x16x32_bf16(af[mi], bfr[ni],
                                                              acc[mi][ni], 0, 0, 0);
  }

#pragma unroll
  for (int mi = 0; mi < 2; ++mi)
#pragma unroll
    for (int r = 0; r < 4; ++r) {
      const int m = m0 + wm + mi * 16 + quad * 4 + r;
#pragma unroll
      for (int ni = 0; ni < 4; ++ni) {
        const int n = n0 + wn + ni * 16 + l15;
        out[(size_t)m * Dmodel + n] = acc[mi][ni][r] + bias[n];
      }
    }
}

// ---------------- fused causal attention (transposed-S, r7 tiling) -----------
// Round-9: round-7 structure (16 q/wave, 64 q/block, LDS 49 KB -> 3 blocks/CU)
// + transposed-S operand swap: S^T = K*Q^T puts 4 CONSECUTIVE keys per lane
// for one q-row -> P round-trip is 8 packed ds_write_b64 (was 32 scattered
// ds_write_b16, the 557k-conflict source); PV becomes O^T = V^T*P^T with the
// SAME V/P LDS read patterns; l is one scalar/lane; ctx stores packed b64.
// Diagonal tiles compute only live column-tiles (wave-uniform bounds).
__global__ void __launch_bounds__(256) attn_fused(const bf16* __restrict__ Q,
                                                  const bf16* __restrict__ K,
                                                  const bf16* __restrict__ Vt,
                                                  bf16* __restrict__ ctx) {
  __shared__ __align__(16) bf16 Ks[8 * 128 * 8];   // [kc][row][8]  16 KB
  __shared__ __align__(16) bf16 Vs[16 * 64 * 8];   // [jc][d][8]    16 KB
  __shared__ __align__(16) bf16 plds[4][16][136];  // per-wave P [qrow][key] 17.4 KB

  const int tid = threadIdx.x;
  const int w = tid >> 6, lane = tid & 63;
  const int l15 = lane & 15, quad = lane >> 4;

  // longest-first: qt descending outer, (h,b) inner (stride 32 -> same XCD)
  const int l = blockIdx.x;                 // 1024 blocks
  const int qt = (Tseq / 64 - 1) - (l >> 5);
  const int hb = l & 31;
  const int h = hb & 15, b = hb >> 4;
  const int bh = b * Hn + h;
  const int qb = qt * 64 + w * 16;

  const bf16* Qb = Q + (size_t)bh * Tseq * DKd;
  const bf16* Kb = K + (size_t)bh * Tseq * DKd;
  const bf16* Vb = Vt + (size_t)bh * DKd * Tseq;

  // Q fragment, B-operand role: n=l15 -> q-row, k=quad*8+j -> dk
  bf16x8 aq0 = *(const bf16x8*)(Qb + (size_t)(qb + l15) * DKd + quad * 8);
  bf16x8 aq1 = *(const bf16x8*)(Qb + (size_t)(qb + l15) * DKd + 32 + quad * 8);

  f32x4 zero = {0.f, 0.f, 0.f, 0.f};
  f32x4 oacc[4];
#pragma unroll
  for (int nd = 0; nd < 4; ++nd) oacc[nd] = zero;
  f32x4 lacc = zero;

  bf16x8 onesf;
#pragma unroll
  for (int i = 0; i < 8; ++i) onesf[i] = (bf16)1.0f;

  const int qmax = qt * 64 + 48;
  for (int j0 = 0; j0 <= qmax; j0 += 128) {
    __syncthreads();
#pragma unroll
    for (int p = 0; p < 4; ++p) {
      const int c = p * 256 + tid;
      gld_lds16(Kb + (size_t)(j0 + (c & 127)) * DKd + (c >> 7) * 8,
                (void*)(Ks + c * 8));
      gld_lds16(Vb + (size_t)(c & 63) * Tseq + j0 + (c >> 6) * 8,
                (void*)(Vs + c * 8));
    }
    __syncthreads();

    if (j0 + 128 <= qb) {
      // ---------- fully unmasked tile ----------
      f32x4 s[8];
#pragma unroll
      for (int ct = 0; ct < 8; ++ct) s[ct] = zero;
#pragma unroll
      for (int ct = 0; ct < 8; ++ct) {
        bf16x8 bk0 = *(const bf16x8*)(Ks + ((quad)*128 + ct * 16 + l15) * 8);
        bf16x8 bk1 = *(const bf16x8*)(Ks + ((4 + quad) * 128 + ct * 16 + l15) * 8);
        s[ct] = __builtin_amdgcn_mfma_f32_16x16x32_bf16(bk0, aq0, s[ct], 0, 0, 0);
        s[ct] = __builtin_amdgcn_mfma_f32_16x16x32_bf16(bk1, aq1, s[ct], 0, 0, 0);
      }
#pragma unroll
      for (int ct = 0; ct < 8; ++ct)
        pack4_store(&plds[w][l15][ct * 16 + quad * 4],
                    exp2f(s[ct][0]), exp2f(s[ct][1]),
                    exp2f(s[ct][2]), exp2f(s[ct][3]));
#pragma unroll
      for (int kc = 0; kc < 4; ++kc) {
        bf16x8 bp = *(const bf16x8*)(&plds[w][l15][kc * 32 + quad * 8]);
        lacc = __builtin_amdgcn_mfma_f32_16x16x32_bf16(onesf, bp, lacc, 0, 0, 0);
#pragma unroll
        for (int nd = 0; nd < 4; ++nd) {
          bf16x8 bv = *(const bf16x8*)(Vs + ((kc * 4 + quad) * 64 + nd * 16 + l15) * 8);
          oacc[nd] = __builtin_amdgcn_mfma_f32_16x16x32_bf16(bv, bp, oacc[nd], 0, 0, 0);
        }
      }
    } else if (j0 <= qb) {
      // ---------- diagonal tile: only live column-tiles (wave-uniform) -------
      const int ctl = ((qb - j0) >> 4) + 1;     // 1..8 live 16-col tiles
      const int kclim = (ctl + 1) >> 1;         // live 32-col PV chunks
      for (int ct = 0; ct < ctl; ++ct) {
        bf16x8 bk0 = *(const bf16x8*)(Ks + ((quad)*128 + ct * 16 + l15) * 8);
        bf16x8 bk1 = *(const bf16x8*)(Ks + ((4 + quad) * 128 + ct * 16 + l15) * 8);
        f32x4 s = zero;
        s = __builtin_amdgcn_mfma_f32_16x16x32_bf16(bk0, aq0, s, 0, 0, 0);
        s = __builtin_amdgcn_mfma_f32_16x16x32_bf16(bk1, aq1, s, 0, 0, 0);
        float p[4];
#pragma unroll
        for (int r = 0; r < 4; ++r) {
          p[r] = exp2f(s[r]);
          // mask only possible in the last live tile: key > qrow
          if (ct == ctl - 1 && (j0 + ct * 16 + quad * 4 + r > qb + l15)) p[r] = 0.f;
        }
        pack4_store(&plds[w][l15][ct * 16 + quad * 4], p[0], p[1], p[2], p[3]);
      }
      if (ctl < 8)  // zero the 16-col block the last b128 P-read may touch
        pack4_store(&plds[w][l15][ctl * 16 + quad * 4], 0.f, 0.f, 0.f, 0.f);
      for (int kc = 0; kc < kclim; ++kc) {
        bf16x8 bp = *(const bf16x8*)(&plds[w][l15][kc * 32 + quad * 8]);
        lacc = __builtin_amdgcn_mfma_f32_16x16x32_bf16(onesf, bp, lacc, 0, 0, 0);
#pragma unroll
        for (int nd = 0; nd < 4; ++nd) {
          bf16x8 bv = *(const bf16x8*)(Vs + ((kc * 4 + quad) * 64 + nd * 16 + l15) * 8);
          oacc[nd] = __builtin_amdgcn_mfma_f32_16x16x32_bf16(bv, bp, oacc[nd], 0, 0, 0);
        }
      }
    }
  }

  // epilogue: O^T lane layout = q-row l15, d = quad*4 + r (packed b64 stores)
  const float inv = 1.0f / lacc[0];
  bf16* cb = ctx + (size_t)(b * Tseq + qb + l15) * Dmodel + h * DKd + quad * 4;
#pragma unroll
  for (int nd = 0; nd < 4; ++nd)
    pack4_store(cb + nd * 16, oacc[nd][0] * inv, oacc[nd][1] * inv,
                oacc[nd][2] * inv, oacc[nd][3] * inv);
}

// -------------------------------- launcher ------------------------------------
extern "C" void kernel_launch(void* const* d_in, const int* in_sizes, int n_in,
                              void* d_out, int out_size, void* d_ws, size_t ws_size,
                              hipStream_t stream) {
  const float* q = (const float*)d_in[0];
  const float* k = (const float*)d_in[1];
  const float* v = (const float*)d_in[2];
  // d_in[3] = attn_mask (causal, known statically) - unused
  const float* Wq = (const float*)d_in[4];
  const float* bq = (const float*)d_in[5];
  const float* Wk = (const float*)d_in[6];
  const float* bk = (const float*)d_in[7];
  const float* Wv = (const float*)d_in[8];
  const float* bv = (const float*)d_in[9];
  const float* Wo = (const float*)d_in[10];
  const float* bo = (const float*)d_in[11];

  char* ws = (char*)d_ws;
  const size_t MB = 1024 * 1024;
  bf16* Wq_b = (bf16*)(ws + 0 * MB);
  bf16* Wk_b = (bf16*)(ws + 2 * MB);
  bf16* Wv_b = (bf16*)(ws + 4 * MB);
  bf16* Wo_b = (bf16*)(ws + 6 * MB);
  bf16* q_b  = (bf16*)(ws + 8 * MB);   // dead after QKV gemm
  bf16* k_b  = (bf16*)(ws + 16 * MB);
  bf16* v_b  = (bf16*)(ws + 24 * MB);
  bf16* Qh   = (bf16*)(ws + 32 * MB);  // [B,H,T,DK], pre-scaled
  bf16* Kh   = (bf16*)(ws + 40 * MB);  // [B,H,T,DK]
  bf16* Vt   = (bf16*)(ws + 48 * MB);  // [B,H,DK,T]
  bf16* ctx  = (bf16*)(ws + 8 * MB);   // aliases q_b (dead by then)

  const int NACT4 = (Bsz * Tseq * Dmodel) / 4;
  const int NW4 = (Dmodel * Dmodel) / 4;

  CvtArgs ca;
  ca.src[0] = q;  ca.dst[0] = q_b;  ca.n4[0] = NACT4;
  ca.src[1] = k;  ca.dst[1] = k_b;  ca.n4[1] = NACT4;
  ca.src[2] = v;  ca.dst[2] = v_b;  ca.n4[2] = NACT4;
  ca.src[3] = Wq; ca.dst[3] = Wq_b; ca.n4[3] = NW4;
  ca.src[4] = Wk; ca.dst[4] = Wk_b; ca.n4[4] = NW4;
  ca.src[5] = Wv; ca.dst[5] = Wv_b; ca.n4[5] = NW4;
  ca.src[6] = Wo; ca.dst[6] = Wo_b; ca.n4[6] = NW4;
  cvt_f32_bf16<<<dim3(512, 7), 256, 0, stream>>>(ca);

  const float SC = 0.125f * 1.4426950408889634f;  // 1/sqrt(DK) * log2(e)
  GemmArgs ga;
  ga.A[0] = q_b; ga.W[0] = Wq_b; ga.bias[0] = bq; ga.out[0] = Qh; ga.mode[0] = 0; ga.scale[0] = SC;
  ga.A[1] = k_b; ga.W[1] = Wk_b; ga.bias[1] = bk; ga.out[1] = Kh; ga.mode[1] = 0; ga.scale[1] = 1.f;
  ga.A[2] = v_b; ga.W[2] = Wv_b; ga.bias[2] = bv; ga.out[2] = Vt; ga.mode[2] = 1; ga.scale[2] = 1.f;
  gemm_qkv<<<dim3(768), 256, 0, stream>>>(ga);

  attn_fused<<<dim3((Tseq / 64) * Hn * Bsz), 256, 0, stream>>>(Qh, Kh, Vt, ctx);

  gemm_out64<<<dim3(512), 256, 0, stream>>>(ctx, Wo_b, bo, (float*)d_out);
}